// Round 1
// baseline (165.498 us; speedup 1.0000x reference)
//
#include <hip/hip_runtime.h>
#include <stdint.h>

// Problem dims
#define TDIM 4096
#define HDIM 2048   // N and K of the GEMM

// GEMM tile
#define BM 128
#define BN 128
#define BK 32

typedef short short8 __attribute__((ext_vector_type(8)));
typedef float f32x4 __attribute__((ext_vector_type(4)));

__device__ __forceinline__ uint16_t f2bf(float f) {
  uint32_t u = __builtin_bit_cast(uint32_t, f);
  u += 0x7fffu + ((u >> 16) & 1u);          // round-to-nearest-even
  return (uint16_t)(u >> 16);
}
__device__ __forceinline__ float bf2f(uint16_t h) {
  uint32_t u = ((uint32_t)h) << 16;
  return __builtin_bit_cast(float, u);
}

__device__ __forceinline__ void async_copy16(const void* gsrc, void* ldst) {
  __builtin_amdgcn_global_load_lds(
      (const __attribute__((address_space(1))) uint32_t*)gsrc,
      (__attribute__((address_space(3))) uint32_t*)ldst,
      16, 0, 0);
}

// ---------------- convert x (fp32 -> bf16), 8 elems/thread ----------------
__global__ void cvt_x(const float* __restrict__ in, uint16_t* __restrict__ out) {
  size_t i = ((size_t)blockIdx.x * 256 + threadIdx.x) * 8;
  float4 v0 = *(const float4*)(in + i);
  float4 v1 = *(const float4*)(in + i + 4);
  union { uint16_t h[8]; uint4 v; } o;
  o.h[0] = f2bf(v0.x); o.h[1] = f2bf(v0.y); o.h[2] = f2bf(v0.z); o.h[3] = f2bf(v0.w);
  o.h[4] = f2bf(v1.x); o.h[5] = f2bf(v1.y); o.h[6] = f2bf(v1.z); o.h[7] = f2bf(v1.w);
  *(uint4*)(out + i) = o.v;
}

// -------- transpose + convert B[h][k] (fp32) -> Bt[k][h] (bf16) ----------
__global__ void transpose_cvt(const float* __restrict__ B, uint16_t* __restrict__ Bt) {
  __shared__ uint16_t tile[64][65];
  const int k0 = blockIdx.y * 64;  // contraction index h of B (rows)
  const int n0 = blockIdx.x * 64;  // output index k of B (cols)
  const int tid = threadIdx.x;
  for (int i = 0; i < 16; ++i) {
    int idx = i * 256 + tid;
    int r = idx >> 6, c = idx & 63;
    tile[r][c] = f2bf(B[(size_t)(k0 + r) * HDIM + n0 + c]);
  }
  __syncthreads();
  for (int i = 0; i < 16; ++i) {
    int idx = i * 256 + tid;
    int r = idx >> 6, c = idx & 63;   // r: n index, c: k index
    Bt[(size_t)(n0 + r) * HDIM + k0 + c] = tile[c][r];
  }
}

// ---------------- GEMM: S[t][n] = sum_k A[t][k] * Bt[n][k] ----------------
// A: [TDIM][HDIM] bf16 row-major (K contiguous); Bt: [HDIM][HDIM] bf16 (K contiguous)
// S: [TDIM][HDIM] bf16
__global__ __launch_bounds__(256) void gemm_bf16(
    const uint16_t* __restrict__ A, const uint16_t* __restrict__ Bt,
    uint16_t* __restrict__ S) {
  __shared__ __align__(16) uint16_t As[BM * BK];
  __shared__ __align__(16) uint16_t Bs[BN * BK];

  const int tid  = threadIdx.x;
  const int lane = tid & 63;
  const int wave = tid >> 6;
  const int wm = (wave >> 1) * 64;   // wave row offset within tile
  const int wn = (wave & 1) * 64;    // wave col offset within tile
  const int m0 = blockIdx.y * BM;
  const int n0 = blockIdx.x * BN;

  f32x4 acc[4][4] = {};

  // staging: lane l covers row (wave*16 + l/4), bytes (l%4)*16 of the 64B row
  const int srow = wave * 16 + (lane >> 2);
  const int scol = (lane & 3) * 16;  // bytes
  const char* aptr = (const char*)A + ((size_t)(m0 + srow) * HDIM) * 2 + scol;
  const char* bptr = (const char*)Bt + ((size_t)(n0 + srow) * HDIM) * 2 + scol;
  char* As_base = (char*)As + wave * 1024;   // + lane*16 implied by HW
  char* Bs_base = (char*)Bs + wave * 1024;
  const size_t rowskip = (size_t)64 * HDIM * 2;  // 64 rows down

  const int fr = lane & 15;
  const int fq = lane >> 4;

  for (int kt = 0; kt < HDIM / BK; ++kt) {
    __syncthreads();
    async_copy16(aptr,           As_base);
    async_copy16(aptr + rowskip, As_base + 4096);
    async_copy16(bptr,           Bs_base);
    async_copy16(bptr + rowskip, Bs_base + 4096);
    aptr += BK * 2;
    bptr += BK * 2;
    asm volatile("s_waitcnt vmcnt(0)" ::: "memory");
    __syncthreads();

    short8 af[4], bfr[4];
#pragma unroll
    for (int im = 0; im < 4; ++im)
      af[im] = *(const short8*)&As[(wm + im * 16 + fr) * BK + fq * 8];
#pragma unroll
    for (int in = 0; in < 4; ++in)
      bfr[in] = *(const short8*)&Bs[(wn + in * 16 + fr) * BK + fq * 8];
#pragma unroll
    for (int im = 0; im < 4; ++im)
#pragma unroll
      for (int in = 0; in < 4; ++in)
        acc[im][in] = __builtin_amdgcn_mfma_f32_16x16x32_bf16(
            af[im], bfr[in], acc[im][in], 0, 0, 0);
  }

  // epilogue: D[row][col], col = lane&15, row = (lane>>4)*4 + r
#pragma unroll
  for (int im = 0; im < 4; ++im) {
#pragma unroll
    for (int in = 0; in < 4; ++in) {
      int col  = n0 + wn + in * 16 + fr;
      int rowb = m0 + wm + im * 16 + fq * 4;
#pragma unroll
      for (int r = 0; r < 4; ++r)
        S[(size_t)(rowb + r) * HDIM + col] = f2bf(acc[im][in][r]);
    }
  }
}

// ---------------- causal exp-decay conv (linear recurrence) ----------------
// out[t][h] = s[t][h] + a[h]*out[t-1][h]; |a| <= 0.03125 so 16-step warmup
// makes each 64-row strip independent (truncation ~1e-25).
#define TT 64
#define WARM 16
__global__ void conv_scan(const uint16_t* __restrict__ S, const float* __restrict__ a,
                          float* __restrict__ out) {
  const int h  = blockIdx.x * 256 + threadIdx.x;
  const int t0 = blockIdx.y * TT;
  const float av = a[h];
  float acc = 0.f;
  int tstart = t0 - WARM;
  if (tstart < 0) tstart = 0;
  for (int t = tstart; t < t0 + TT; ++t) {
    float s = bf2f(S[(size_t)t * HDIM + h]);
    acc = av * acc + s;
    if (t >= t0) out[(size_t)t * HDIM + h] = acc;
  }
}

extern "C" void kernel_launch(void* const* d_in, const int* in_sizes, int n_in,
                              void* d_out, int out_size, void* d_ws, size_t ws_size,
                              hipStream_t stream) {
  const float* x = (const float*)d_in[0];   // (T, H)
  const float* a = (const float*)d_in[1];   // (H,)
  const float* B = (const float*)d_in[2];   // (H, H)
  float* out = (float*)d_out;               // (1, T, H) fp32

  uint16_t* xb  = (uint16_t*)d_ws;                                        // 16 MB
  uint16_t* Btb = (uint16_t*)((char*)d_ws + (size_t)16 * 1024 * 1024);    //  8 MB
  uint16_t* S   = (uint16_t*)((char*)d_ws + (size_t)24 * 1024 * 1024);    // 16 MB

  // x -> bf16: T*H/8 threads
  cvt_x<<<(TDIM * HDIM) / (8 * 256), 256, 0, stream>>>(x, xb);
  // B -> Bt bf16
  transpose_cvt<<<dim3(HDIM / 64, HDIM / 64), 256, 0, stream>>>(B, Btb);
  // S = x @ B
  gemm_bf16<<<dim3(HDIM / BN, TDIM / BM), 256, 0, stream>>>(xb, Btb, S);
  // recurrence
  conv_scan<<<dim3(HDIM / 256, TDIM / TT), 256, 0, stream>>>(S, a, out);
}

// Round 2
// 152.195 us; speedup vs baseline: 1.0874x; 1.0874x over previous
//
#include <hip/hip_runtime.h>
#include <stdint.h>

// Problem dims
#define TDIM 4096
#define HDIM 2048   // N and K of the GEMM

// GEMM tile
#define BM 128
#define BN 128
#define BK 32

typedef short short8 __attribute__((ext_vector_type(8)));
typedef float f32x4 __attribute__((ext_vector_type(4)));

__device__ __forceinline__ uint16_t f2bf(float f) {
  uint32_t u = __builtin_bit_cast(uint32_t, f);
  u += 0x7fffu + ((u >> 16) & 1u);          // round-to-nearest-even
  return (uint16_t)(u >> 16);
}
__device__ __forceinline__ float bf2f(uint32_t h) {   // low 16 bits used
  uint32_t u = h << 16;
  return __builtin_bit_cast(float, u);
}

__device__ __forceinline__ void async_copy16(const void* gsrc, void* ldst) {
  __builtin_amdgcn_global_load_lds(
      (const __attribute__((address_space(1))) uint32_t*)gsrc,
      (__attribute__((address_space(3))) uint32_t*)ldst,
      16, 0, 0);
}

// ---------------- convert x (fp32 -> bf16), 8 elems/thread ----------------
__global__ void cvt_x(const float* __restrict__ in, uint16_t* __restrict__ out) {
  size_t i = ((size_t)blockIdx.x * 256 + threadIdx.x) * 8;
  float4 v0 = *(const float4*)(in + i);
  float4 v1 = *(const float4*)(in + i + 4);
  union { uint16_t h[8]; uint4 v; } o;
  o.h[0] = f2bf(v0.x); o.h[1] = f2bf(v0.y); o.h[2] = f2bf(v0.z); o.h[3] = f2bf(v0.w);
  o.h[4] = f2bf(v1.x); o.h[5] = f2bf(v1.y); o.h[6] = f2bf(v1.z); o.h[7] = f2bf(v1.w);
  *(uint4*)(out + i) = o.v;
}

// -------- transpose + convert B[h][k] (fp32) -> Bt[k][h] (bf16) ----------
__global__ void transpose_cvt(const float* __restrict__ B, uint16_t* __restrict__ Bt) {
  __shared__ uint16_t tile[64][65];
  const int k0 = blockIdx.y * 64;  // contraction index h of B (rows)
  const int n0 = blockIdx.x * 64;  // output index k of B (cols)
  const int tid = threadIdx.x;
  for (int i = 0; i < 16; ++i) {
    int idx = i * 256 + tid;
    int r = idx >> 6, c = idx & 63;
    tile[r][c] = f2bf(B[(size_t)(k0 + r) * HDIM + n0 + c]);
  }
  __syncthreads();
  for (int i = 0; i < 16; ++i) {
    int idx = i * 256 + tid;
    int r = idx >> 6, c = idx & 63;   // r: n index, c: k index
    Bt[(size_t)(n0 + r) * HDIM + k0 + c] = tile[c][r];
  }
}

// ---------------- GEMM: S[t][n] = sum_k A[t][k] * Bt[n][k] ----------------
// A: [TDIM][HDIM] bf16 row-major (K contiguous); Bt: [HDIM][HDIM] bf16 (K contiguous)
// S: [TDIM][HDIM] bf16
// 512 threads = 8 waves; wave tile 64x32; XOR-swizzled LDS chunk placement.
__global__ __launch_bounds__(512) void gemm_bf16(
    const uint16_t* __restrict__ A, const uint16_t* __restrict__ Bt,
    uint16_t* __restrict__ S) {
  __shared__ __align__(16) uint16_t As[BM * BK];   // 8 KB
  __shared__ __align__(16) uint16_t Bs[BN * BK];   // 8 KB

  const int tid  = threadIdx.x;
  const int lane = tid & 63;
  const int wave = tid >> 6;            // 0..7
  const int wm = (wave >> 2) * 64;      // wave row offset within tile {0,64}
  const int wn = (wave & 3) * 32;       // wave col offset within tile {0,32,64,96}
  const int m0 = blockIdx.y * BM;
  const int n0 = blockIdx.x * BN;

  f32x4 acc[4][2] = {};

  // --- staging: wave w copies 16 rows of A and 16 rows of B ---
  // LDS slot for (row, chunk) is chunk ^ swz(row); lane l writes slot (l&3)
  // so it must FETCH global chunk (l&3) ^ swz(l>>2).  swz(r)=(r&3)^((r>>2)&3)
  const int rloc  = lane >> 2;                       // 0..15
  const int swzl  = (rloc & 3) ^ ((rloc >> 2) & 3);
  const int gchunk = (lane & 3) ^ swzl;              // 16B chunk to fetch
  const char* aptr = (const char*)A +
      ((size_t)(m0 + wave * 16 + rloc) * HDIM + gchunk * 8) * 2;
  const char* bptr = (const char*)Bt +
      ((size_t)(n0 + wave * 16 + rloc) * HDIM + gchunk * 8) * 2;
  char* As_base = (char*)As + wave * 1024;   // + lane*16 implied by HW
  char* Bs_base = (char*)Bs + wave * 1024;

  // --- fragment read indices ---
  const int fr = lane & 15;
  const int fq = lane >> 4;                          // 0..3
  const int swzf = (fr & 3) ^ ((fr >> 2) & 3);
  const int rchunk = fq ^ swzf;                      // swizzled chunk slot

  for (int kt = 0; kt < HDIM / BK; ++kt) {
    __syncthreads();
    async_copy16(aptr, As_base);
    async_copy16(bptr, Bs_base);
    aptr += BK * 2;
    bptr += BK * 2;
    asm volatile("s_waitcnt vmcnt(0)" ::: "memory");
    __syncthreads();

    short8 af[4], bfr[2];
#pragma unroll
    for (int im = 0; im < 4; ++im)
      af[im] = *(const short8*)&As[(wm + im * 16 + fr) * BK + rchunk * 8];
#pragma unroll
    for (int in = 0; in < 2; ++in)
      bfr[in] = *(const short8*)&Bs[(wn + in * 16 + fr) * BK + rchunk * 8];
#pragma unroll
    for (int im = 0; im < 4; ++im)
#pragma unroll
      for (int in = 0; in < 2; ++in)
        acc[im][in] = __builtin_amdgcn_mfma_f32_16x16x32_bf16(
            af[im], bfr[in], acc[im][in], 0, 0, 0);
  }

  // epilogue: D[row][col], col = lane&15, row = (lane>>4)*4 + r
#pragma unroll
  for (int im = 0; im < 4; ++im) {
#pragma unroll
    for (int in = 0; in < 2; ++in) {
      int col  = n0 + wn + in * 16 + fr;
      int rowb = m0 + wm + im * 16 + fq * 4;
#pragma unroll
      for (int r = 0; r < 4; ++r)
        S[(size_t)(rowb + r) * HDIM + col] = f2bf(acc[im][in][r]);
    }
  }
}

// ---------------- causal exp-decay conv (linear recurrence) ----------------
// out[t][h] = s[t][h] + a[h]*out[t-1][h]; |a| <= 0.03125 so a 16-step warmup
// makes each strip independent (truncation ~1e-25).
// 4 h-columns per thread; uint2 bf16 loads, float4 stores.
#define TT 16
#define WARM 16
__global__ void conv_scan(const uint16_t* __restrict__ S, const float* __restrict__ a,
                          float* __restrict__ out) {
  const int h  = (blockIdx.x * 256 + threadIdx.x) * 4;
  const int t0 = blockIdx.y * TT;
  const float4 av = *(const float4*)(a + h);
  float a0 = 0.f, a1 = 0.f, a2 = 0.f, a3 = 0.f;
  if (t0 > 0) {
#pragma unroll
    for (int i = 0; i < WARM; ++i) {
      int t = t0 - WARM + i;
      uint2 sv = *(const uint2*)(S + (size_t)t * HDIM + h);
      a0 = av.x * a0 + bf2f(sv.x & 0xffffu);
      a1 = av.y * a1 + bf2f(sv.x >> 16);
      a2 = av.z * a2 + bf2f(sv.y & 0xffffu);
      a3 = av.w * a3 + bf2f(sv.y >> 16);
    }
  }
#pragma unroll
  for (int i = 0; i < TT; ++i) {
    int t = t0 + i;
    uint2 sv = *(const uint2*)(S + (size_t)t * HDIM + h);
    a0 = av.x * a0 + bf2f(sv.x & 0xffffu);
    a1 = av.y * a1 + bf2f(sv.x >> 16);
    a2 = av.z * a2 + bf2f(sv.y & 0xffffu);
    a3 = av.w * a3 + bf2f(sv.y >> 16);
    float4 o = make_float4(a0, a1, a2, a3);
    *(float4*)(out + (size_t)t * HDIM + h) = o;
  }
}

extern "C" void kernel_launch(void* const* d_in, const int* in_sizes, int n_in,
                              void* d_out, int out_size, void* d_ws, size_t ws_size,
                              hipStream_t stream) {
  const float* x = (const float*)d_in[0];   // (T, H)
  const float* a = (const float*)d_in[1];   // (H,)
  const float* B = (const float*)d_in[2];   // (H, H)
  float* out = (float*)d_out;               // (1, T, H) fp32

  uint16_t* xb  = (uint16_t*)d_ws;                                        // 16 MB
  uint16_t* Btb = (uint16_t*)((char*)d_ws + (size_t)16 * 1024 * 1024);    //  8 MB
  uint16_t* S   = (uint16_t*)((char*)d_ws + (size_t)24 * 1024 * 1024);    // 16 MB

  // x -> bf16
  cvt_x<<<(TDIM * HDIM) / (8 * 256), 256, 0, stream>>>(x, xb);
  // B -> Bt bf16
  transpose_cvt<<<dim3(HDIM / 64, HDIM / 64), 256, 0, stream>>>(B, Btb);
  // S = x @ B   (512 blocks x 512 threads, 128x128 tile)
  gemm_bf16<<<dim3(HDIM / BN, TDIM / BM), 512, 0, stream>>>(xb, Btb, S);
  // recurrence
  conv_scan<<<dim3(HDIM / (256 * 4), TDIM / TT), 256, 0, stream>>>(S, a, out);
}

// Round 3
// 140.381 us; speedup vs baseline: 1.1789x; 1.0842x over previous
//
#include <hip/hip_runtime.h>
#include <stdint.h>

// Problem dims
#define TDIM 4096
#define HDIM 2048   // N and K of the GEMM

// GEMM tile
#define BM 128
#define BN 128
#define BK 64

typedef short short8 __attribute__((ext_vector_type(8)));
typedef float f32x4 __attribute__((ext_vector_type(4)));

__device__ __forceinline__ uint16_t f2bf(float f) {
  uint32_t u = __builtin_bit_cast(uint32_t, f);
  u += 0x7fffu + ((u >> 16) & 1u);          // round-to-nearest-even
  return (uint16_t)(u >> 16);
}
__device__ __forceinline__ float bf2f(uint32_t h) {   // low 16 bits used
  uint32_t u = h << 16;
  return __builtin_bit_cast(float, u);
}

__device__ __forceinline__ void async_copy16(const void* gsrc, void* ldst) {
  __builtin_amdgcn_global_load_lds(
      (const __attribute__((address_space(1))) uint32_t*)gsrc,
      (__attribute__((address_space(3))) uint32_t*)ldst,
      16, 0, 0);
}

// ------------- prep: cvt x (fp32->bf16) + transpose/cvt B -> Bt -------------
// blocks [0, 4096): convert x, 8 elems/thread
// blocks [4096, 5120): 64x64 transpose tiles of B
__global__ void prep(const float* __restrict__ x, const float* __restrict__ B,
                     uint16_t* __restrict__ xb, uint16_t* __restrict__ Bt) {
  __shared__ uint16_t tile[64][68];   // 68: 136B row stride, 8B-aligned cols
  const int t = threadIdx.x;
  if (blockIdx.x < 4096) {
    size_t i = ((size_t)blockIdx.x * 256 + t) * 8;
    float4 v0 = *(const float4*)(x + i);
    float4 v1 = *(const float4*)(x + i + 4);
    union { uint16_t h[8]; uint4 v; } o;
    o.h[0] = f2bf(v0.x); o.h[1] = f2bf(v0.y); o.h[2] = f2bf(v0.z); o.h[3] = f2bf(v0.w);
    o.h[4] = f2bf(v1.x); o.h[5] = f2bf(v1.y); o.h[6] = f2bf(v1.z); o.h[7] = f2bf(v1.w);
    *(uint4*)(xb + i) = o.v;
  } else {
    const int bid = blockIdx.x - 4096;
    const int n0 = (bid & 31) * 64;   // column tile of B (output row of Bt)
    const int k0 = (bid >> 5) * 64;   // row tile of B (contraction index)
    {
      const int r  = t >> 4;          // 0..15
      const int c4 = (t & 15) * 4;    // 0..60
#pragma unroll
      for (int i = 0; i < 4; ++i) {
        int rr = r + i * 16;
        float4 v = *(const float4*)&B[(size_t)(k0 + rr) * HDIM + n0 + c4];
        union { uint16_t h[4]; uint2 u; } o;
        o.h[0] = f2bf(v.x); o.h[1] = f2bf(v.y); o.h[2] = f2bf(v.z); o.h[3] = f2bf(v.w);
        *(uint2*)&tile[rr][c4] = o.u;
      }
    }
    __syncthreads();
    {
      const int nr = t >> 2;          // 0..63
      const int kc = (t & 3) * 4;
#pragma unroll
      for (int i = 0; i < 4; ++i) {
        int kk = kc + i * 16;
        union { uint16_t h[4]; uint2 u; } o;
        o.h[0] = tile[kk][nr];     o.h[1] = tile[kk + 1][nr];
        o.h[2] = tile[kk + 2][nr]; o.h[3] = tile[kk + 3][nr];
        *(uint2*)&Bt[(size_t)(n0 + nr) * HDIM + k0 + kk] = o.u;
      }
    }
  }
}

// ---------------- GEMM: S[t][n] = sum_k A[t][k] * Bt[n][k] ----------------
// Double-buffered LDS, raw s_barrier + fine vmcnt(4): next tile's
// global_load_lds stays in flight across the barrier (AITER pattern).
// 512 threads = 8 waves; wave tile 64x32; BK=64 -> 32 iters, 16 MFMA/iter.
__global__ __launch_bounds__(512, 4) void gemm_bf16(
    const uint16_t* __restrict__ A, const uint16_t* __restrict__ Bt,
    uint16_t* __restrict__ S) {
  __shared__ __align__(16) uint16_t As[2][BM * BK];   // 2 x 16 KB
  __shared__ __align__(16) uint16_t Bs[2][BN * BK];   // 2 x 16 KB

  const int tid  = threadIdx.x;
  const int lane = tid & 63;
  const int wave = tid >> 6;            // 0..7
  const int wm = (wave >> 2) * 64;      // wave row offset {0,64}
  const int wn = (wave & 3) * 32;       // wave col offset {0,32,64,96}
  const int m0 = blockIdx.y * BM;
  const int n0 = blockIdx.x * BN;

  f32x4 acc[4][2] = {};

  // --- staging: row = 128B (64 bf16) = 8 chunks of 16B; slot c holds global
  // chunk c ^ (row&7).  One copy instr = 8 rows; lane l: row l>>3, slot l&7,
  // so it fetches global chunk (l&7)^(l>>3).
  const int lr = lane >> 3;             // 0..7
  const int gc = (lane & 7) ^ lr;       // swizzled global chunk
  const char* aA0 = (const char*)A  + ((size_t)(m0 + wave * 16 + lr)     * HDIM + gc * 8) * 2;
  const char* aA1 = (const char*)A  + ((size_t)(m0 + wave * 16 + 8 + lr) * HDIM + gc * 8) * 2;
  const char* aB0 = (const char*)Bt + ((size_t)(n0 + wave * 16 + lr)     * HDIM + gc * 8) * 2;
  const char* aB1 = (const char*)Bt + ((size_t)(n0 + wave * 16 + 8 + lr) * HDIM + gc * 8) * 2;

  const int fr = lane & 15;
  const int fq = lane >> 4;             // 0..3

#define ISSUE(kt, b)                                                        \
  do {                                                                      \
    size_t koff = (size_t)(kt) * (BK * 2);                                  \
    char* dA = (char*)As + (b) * 16384 + (wave * 16) * 128;                 \
    char* dB = (char*)Bs + (b) * 16384 + (wave * 16) * 128;                 \
    async_copy16(aA0 + koff, dA);                                           \
    async_copy16(aA1 + koff, dA + 1024);                                    \
    async_copy16(aB0 + koff, dB);                                           \
    async_copy16(aB1 + koff, dB + 1024);                                    \
  } while (0)

  ISSUE(0, 0);
  const int NKT = HDIM / BK;            // 32
  for (int kt = 0; kt < NKT; ++kt) {
    int nkt = (kt + 1 < NKT) ? kt + 1 : kt;   // dummy reload on last iter
    ISSUE(nkt, (kt + 1) & 1);
    // wait only for tile kt's 4 loads (4 newer stay in flight), then barrier
    asm volatile("s_waitcnt vmcnt(4)\n\ts_barrier" ::: "memory");

    const uint16_t* as = &As[kt & 1][0];
    const uint16_t* bs = &Bs[kt & 1][0];
#pragma unroll
    for (int s = 0; s < 2; ++s) {
      short8 af[4], bfr[2];
#pragma unroll
      for (int im = 0; im < 4; ++im) {
        int row = wm + im * 16 + fr;
        af[im] = *(const short8*)&as[row * 64 + (((s * 4 + fq) ^ (row & 7)) * 8)];
      }
#pragma unroll
      for (int in = 0; in < 2; ++in) {
        int row = wn + in * 16 + fr;
        bfr[in] = *(const short8*)&bs[row * 64 + (((s * 4 + fq) ^ (row & 7)) * 8)];
      }
#pragma unroll
      for (int im = 0; im < 4; ++im)
#pragma unroll
        for (int in = 0; in < 2; ++in)
          acc[im][in] = __builtin_amdgcn_mfma_f32_16x16x32_bf16(
              af[im], bfr[in], acc[im][in], 0, 0, 0);
    }
    // everyone done reading buf[kt&1]; safe to overwrite next iteration
    asm volatile("s_barrier" ::: "memory");
  }
#undef ISSUE

  // epilogue: D[row][col], col = lane&15, row = (lane>>4)*4 + r
#pragma unroll
  for (int im = 0; im < 4; ++im) {
#pragma unroll
    for (int in = 0; in < 2; ++in) {
      int col  = n0 + wn + in * 16 + fr;
      int rowb = m0 + wm + im * 16 + fq * 4;
#pragma unroll
      for (int r = 0; r < 4; ++r)
        S[(size_t)(rowb + r) * HDIM + col] = f2bf(acc[im][in][r]);
    }
  }
}

// ---------------- causal exp-decay conv (linear recurrence) ----------------
// out[t][h] = s[t][h] + a[h]*out[t-1][h]; |a| <= 0.03125 so a 16-step warmup
// makes each strip independent (truncation ~1e-25).
#define TT 16
#define WARM 16
__global__ void conv_scan(const uint16_t* __restrict__ S, const float* __restrict__ a,
                          float* __restrict__ out) {
  const int h  = (blockIdx.x * 256 + threadIdx.x) * 4;
  const int t0 = blockIdx.y * TT;
  const float4 av = *(const float4*)(a + h);
  float a0 = 0.f, a1 = 0.f, a2 = 0.f, a3 = 0.f;
  if (t0 > 0) {
#pragma unroll
    for (int i = 0; i < WARM; ++i) {
      int t = t0 - WARM + i;
      uint2 sv = *(const uint2*)(S + (size_t)t * HDIM + h);
      a0 = av.x * a0 + bf2f(sv.x & 0xffffu);
      a1 = av.y * a1 + bf2f(sv.x >> 16);
      a2 = av.z * a2 + bf2f(sv.y & 0xffffu);
      a3 = av.w * a3 + bf2f(sv.y >> 16);
    }
  }
#pragma unroll
  for (int i = 0; i < TT; ++i) {
    int t = t0 + i;
    uint2 sv = *(const uint2*)(S + (size_t)t * HDIM + h);
    a0 = av.x * a0 + bf2f(sv.x & 0xffffu);
    a1 = av.y * a1 + bf2f(sv.x >> 16);
    a2 = av.z * a2 + bf2f(sv.y & 0xffffu);
    a3 = av.w * a3 + bf2f(sv.y >> 16);
    float4 o = make_float4(a0, a1, a2, a3);
    *(float4*)(out + (size_t)t * HDIM + h) = o;
  }
}

extern "C" void kernel_launch(void* const* d_in, const int* in_sizes, int n_in,
                              void* d_out, int out_size, void* d_ws, size_t ws_size,
                              hipStream_t stream) {
  const float* x = (const float*)d_in[0];   // (T, H)
  const float* a = (const float*)d_in[1];   // (H,)
  const float* B = (const float*)d_in[2];   // (H, H)
  float* out = (float*)d_out;               // (1, T, H) fp32

  uint16_t* xb  = (uint16_t*)d_ws;                                        // 16 MB
  uint16_t* Btb = (uint16_t*)((char*)d_ws + (size_t)16 * 1024 * 1024);    //  8 MB
  uint16_t* S   = (uint16_t*)((char*)d_ws + (size_t)24 * 1024 * 1024);    // 16 MB

  // x -> bf16  and  B -> Bt bf16 (fused)
  prep<<<4096 + 1024, 256, 0, stream>>>(x, B, xb, Btb);
  // S = x @ B   (512 blocks x 512 threads, 128x128 tile, BK=64, dbuf)
  gemm_bf16<<<dim3(HDIM / BN, TDIM / BM), 512, 0, stream>>>(xb, Btb, S);
  // recurrence
  conv_scan<<<dim3(HDIM / (256 * 4), TDIM / TT), 256, 0, stream>>>(S, a, out);
}